// Round 6
// baseline (196183.496 us; speedup 1.0000x reference)
//
#include <hip/hip_runtime.h>

// GRUModel: 2-layer GRU (T=16384, IN=512, H=1024) + BatchNorm(train) + FC(H->1)
//
// R6: XCD-local recurrence with EXACT seating.
//  - Grid 512 x 256, __launch_bounds__(256,2) => 2 blocks/CU, fully resident,
//    exactly 64 blocks per XCD. First two XCDs to check in become homes for
//    layer0/layer1; their 64 blocks fill 64 seats exactly (no rescue needed;
//    a 1.2ms-timeout rescue kept as insurance, seated in shadow mode).
//  - Recurrent h exchange: 32-slot ring (64KB) in the home XCD's L2. Plain
//    stores by producers + sc0 (L1-bypass) polls by consumers. Producer
//    sentinel-resets slot+16 (15-tick margin; skew<=1 tick by all-gather
//    coupling). Single writer per u64, single L2 => no stale-epoch reads.
//  - Producers ALWAYS dual-publish: ring (plain, only if seated on home XCD)
//    + shadow stream (agent scope, MALL). Consumers: sc0 ring fast path,
//    sticky flip to shadow after 2048 spins => bounded degradation (~R2),
//    never deadlock. Shadow-mode producers skip the ring (avoids cross-XCD
//    dirty-line hazard, R4's fatal bug).
//  - Cross-XCD feed-forward h1->layer1: agent shadow stream, depth-4
//    prefetch; MALL latency paid once as pipeline offset, not per tick.

#define TT 16384
#define IND 512
#define HD 1024
#define SENT 0x7F7F7F7Fu
#define SENT64 0x7F7F7F7F7F7F7F7FULL
#define RM 31

typedef _Float16 h2_t __attribute__((ext_vector_type(2)));
typedef unsigned long long u64;
typedef __attribute__((ext_vector_type(2))) unsigned long long u64x2;

static __device__ __forceinline__ float fdot2f(h2_t a, h2_t b, float c) {
  return __builtin_amdgcn_fdot2(a, b, c, false);
}
static __device__ __forceinline__ h2_t cvt2(float a, float b) {
  h2_t r; r.x = (_Float16)a; r.y = (_Float16)b; return r;
}
static __device__ __forceinline__ float sigm(float v) { return 1.f / (1.f + __expf(-v)); }
static __device__ __forceinline__ float tanh_f(float v) {
  v = fminf(fmaxf(v, -15.f), 15.f);
  float e = __expf(2.f * v);
  return (e - 1.f) / (e + 1.f);
}
static __device__ __forceinline__ u64 aload(const u64* p) {
  return __hip_atomic_load(p, __ATOMIC_RELAXED, __HIP_MEMORY_SCOPE_AGENT);
}
static __device__ __forceinline__ unsigned aload32(const unsigned* p) {
  return __hip_atomic_load(p, __ATOMIC_RELAXED, __HIP_MEMORY_SCOPE_AGENT);
}
static __device__ __forceinline__ void astore(u64* p, u64 v) {
  __hip_atomic_store(p, v, __ATOMIC_RELAXED, __HIP_MEMORY_SCOPE_AGENT);
}

// Reduce 4 per-lane partials across 64 lanes; all lanes get (R,Z,Nx,Nh).
static __device__ __forceinline__ float4 reduce4(float aR, float aZ, float aNx,
                                                 float aNh, int lane) {
  const bool s1 = lane & 1;
  float x1 = s1 ? aZ : aR, y1 = s1 ? aR : aZ;
  x1 += __shfl_xor(y1, 1);
  float x2 = s1 ? aNh : aNx, y2 = s1 ? aNx : aNh;
  x2 += __shfl_xor(y2, 1);
  const bool s2 = lane & 2;
  float z = s2 ? x2 : x1, w = s2 ? x1 : x2;
  z += __shfl_xor(w, 2);
  z += __shfl_xor(z, 4);
  z += __shfl_xor(z, 8);
  z += __shfl_xor(z, 16);
  z += __shfl_xor(z, 32);
  return make_float4(__shfl(z, 0), __shfl(z, 1), __shfl(z, 2), __shfl(z, 3));
}

static __device__ __forceinline__ u64 pack4(float h0, float h1, float h2, float h3) {
  unsigned lo = (unsigned)__builtin_bit_cast(unsigned short, (_Float16)h0) |
                ((unsigned)__builtin_bit_cast(unsigned short, (_Float16)h1) << 16);
  unsigned hi = (unsigned)__builtin_bit_cast(unsigned short, (_Float16)h2) |
                ((unsigned)__builtin_bit_cast(unsigned short, (_Float16)h3) << 16);
  return (u64)lo | ((u64)hi << 32);
}

// Poll this lane's 4 u64 of a slot. Fast path: sc0 loads on the L2-resident
// ring; sticky fallback to the agent-scope shadow stream.
static __device__ __forceinline__ void pollrec(const u64* ploc, const u64* psh,
                                               u64 v[4], bool& viaAgent) {
  if (!viaAgent) {
    int spins = 0;
    for (;;) {
      u64x2 a, b;
      asm volatile("global_load_dwordx4 %0, %2, off sc0\n\t"
                   "global_load_dwordx4 %1, %3, off sc0\n\t"
                   "s_waitcnt vmcnt(0)"
                   : "=v"(a), "=v"(b) : "v"(ploc), "v"(ploc + 2) : "memory");
      bool bad = ((unsigned)a.x == SENT) | ((unsigned)a.y == SENT) |
                 ((unsigned)b.x == SENT) | ((unsigned)b.y == SENT);
      if (!__any(bad)) { v[0] = a.x; v[1] = a.y; v[2] = b.x; v[3] = b.y; return; }
      if (++spins > 2048) { viaAgent = true; break; }
    }
  }
  for (;;) {
    u64 a0 = aload(psh), a1 = aload(psh + 1), a2 = aload(psh + 2), a3 = aload(psh + 3);
    bool ok = ((unsigned)a0 != SENT) & ((unsigned)a1 != SENT) &
              ((unsigned)a2 != SENT) & ((unsigned)a3 != SENT);
    if (!__any(!ok)) { v[0] = a0; v[1] = a1; v[2] = a2; v[3] = a3; return; }
  }
}

__launch_bounds__(256, 2)
__global__ void gru_persistent(
    const float* __restrict__ x,
    const float* __restrict__ wih0, const float* __restrict__ whh0,
    const float* __restrict__ bih0, const float* __restrict__ bhh0,
    const float* __restrict__ wih1, const float* __restrict__ whh1,
    const float* __restrict__ bih1, const float* __restrict__ bhh1,
    u64* h1loc, u64* h2loc, u64* h1x, u64* h2x, float* sums, unsigned* ctrl)
{
  const int tid = threadIdx.x;
  const int wave = tid >> 6;
  const int lane = tid & 63;

  // ---- seating: ctrl[0..7] per-XCD arrivals, [8] claim, [9/10] home+1,
  // [11/12] seat counters ----
  __shared__ int sh_role, sh_seat, sh_fast;
  if (tid == 0) {
    unsigned xcd;
    asm volatile("s_getreg_b32 %0, hwreg(HW_REG_XCC_ID)" : "=s"(xcd));
    xcd &= 7;
    unsigned rank = atomicAdd(&ctrl[xcd], 1u);
    if (rank == 0) {
      unsigned k = atomicAdd(&ctrl[8], 1u);
      if (k < 2)
        __hip_atomic_store(&ctrl[9 + k], xcd + 1, __ATOMIC_RELAXED, __HIP_MEMORY_SCOPE_AGENT);
    }
    unsigned hm0, hm1;
    do { hm0 = aload32(&ctrl[9]); hm1 = aload32(&ctrl[10]); } while (hm0 == 0 || hm1 == 0);
    hm0--; hm1--;
    int role = -1, seat = -1, fast = 1;
    if (xcd == hm0) { unsigned s = atomicAdd(&ctrl[11], 1u); if (s < 64) { role = 0; seat = (int)s; } }
    else if (xcd == hm1) { unsigned s = atomicAdd(&ctrl[12], 1u); if (s < 64) { role = 1; seat = (int)s; } }
    if (role < 0) {
      long long t0 = clock64();
      for (;;) {
        unsigned s0 = aload32(&ctrl[11]), s1 = aload32(&ctrl[12]);
        if (s0 >= 64 && s1 >= 64) break;           // all seated -> exit
        if (clock64() - t0 > 3000000LL) {          // insurance only
          if (s0 < 64) { unsigned s = atomicAdd(&ctrl[11], 1u); if (s < 64) { role = 0; seat = (int)s; fast = 0; break; } }
          if (s1 < 64) { unsigned s = atomicAdd(&ctrl[12], 1u); if (s < 64) { role = 1; seat = (int)s; fast = 0; break; } }
        } else {
          __builtin_amdgcn_s_sleep(16);
        }
      }
    }
    sh_role = role; sh_seat = seat; sh_fast = fast;
  }
  __syncthreads();
  const int role = sh_role;
  if (role < 0) return;
  const int seat = sh_seat;
  const bool ringStore = (sh_fast != 0);  // immutable: producer may use ring
  bool viaAgent = !ringStore;             // consumer mode, sticky

  if (role == 0) {
    // ---------------- layer 0 : wave owns channels ch..ch+3 ----------------
    const int ch = seat * 16 + wave * 4;
    const int myu = ch >> 2;
    h2_t Wx[4][3][4];   // x-part: 8 f16 per gate per channel
    h2_t Wh[4][3][8];   // h-part: 16 f16 per gate per channel
    float bRv[4], bZv[4], bNxv[4], bNhv[4];
#pragma unroll
    for (int cc = 0; cc < 4; ++cc) {
      const int c = ch + cc;
#pragma unroll
      for (int g = 0; g < 3; ++g) {
        const float* pr = wih0 + (size_t)(g * HD + c) * IND + 8 * lane;
#pragma unroll
        for (int j = 0; j < 4; ++j) Wx[cc][g][j] = cvt2(pr[2 * j], pr[2 * j + 1]);
        const float* ph = whh0 + (size_t)(g * HD + c) * HD + 16 * lane;
#pragma unroll
        for (int j = 0; j < 8; ++j) Wh[cc][g][j] = cvt2(ph[2 * j], ph[2 * j + 1]);
      }
      bRv[cc]  = bih0[c] + bhh0[c];
      bZv[cc]  = bih0[HD + c] + bhh0[HD + c];
      bNxv[cc] = bih0[2 * HD + c];
      bNhv[cc] = bhh0[2 * HD + c];
    }
    float hprev[4] = {0.f, 0.f, 0.f, 0.f};
    const float* px0 = x + 8 * lane;
    float4 xa = *(const float4*)px0;
    float4 xb = *(const float4*)(px0 + 4);
    for (int t = 0; t < TT; ++t) {
      h2_t xv[4];
      xv[0] = cvt2(xa.x, xa.y); xv[1] = cvt2(xa.z, xa.w);
      xv[2] = cvt2(xb.x, xb.y); xv[3] = cvt2(xb.z, xb.w);
      if (t + 1 < TT) {
        const float* pn = x + (size_t)(t + 1) * IND + 8 * lane;
        xa = *(const float4*)pn;
        xb = *(const float4*)(pn + 4);
      }
      float aR[4], aZ[4], aNx[4], aNh[4];
#pragma unroll
      for (int cc = 0; cc < 4; ++cc) {
        float r = 0.f, z = 0.f, n = 0.f;
#pragma unroll
        for (int j = 0; j < 4; ++j) {
          r = fdot2f(Wx[cc][0][j], xv[j], r);
          z = fdot2f(Wx[cc][1][j], xv[j], z);
          n = fdot2f(Wx[cc][2][j], xv[j], n);
        }
        aR[cc] = r; aZ[cc] = z; aNx[cc] = n; aNh[cc] = 0.f;
      }
      // h1[t-1]: ring slot (t-1)&31 (home L2) / shadow h1x slot t (agent)
      u64 hv[4];
      pollrec(h1loc + (size_t)((t - 1) & RM) * 256 + 4 * lane,
              h1x + (size_t)t * 256 + 4 * lane, hv, viaAgent);
      h2_t hh[8];
#pragma unroll
      for (int i = 0; i < 4; ++i) {
        hh[2 * i]     = __builtin_bit_cast(h2_t, (unsigned)hv[i]);
        hh[2 * i + 1] = __builtin_bit_cast(h2_t, (unsigned)(hv[i] >> 32));
      }
#pragma unroll
      for (int cc = 0; cc < 4; ++cc) {
        float r = aR[cc], z = aZ[cc], n = aNh[cc];
#pragma unroll
        for (int j = 0; j < 8; ++j) {
          r = fdot2f(Wh[cc][0][j], hh[j], r);
          z = fdot2f(Wh[cc][1][j], hh[j], z);
          n = fdot2f(Wh[cc][2][j], hh[j], n);
        }
        aR[cc] = r; aZ[cc] = z; aNh[cc] = n;
      }
      float hn[4];
#pragma unroll
      for (int cc = 0; cc < 4; ++cc) {
        float4 s = reduce4(aR[cc], aZ[cc], aNx[cc], aNh[cc], lane);
        float r = sigm(s.x + bRv[cc]);
        float zz = sigm(s.y + bZv[cc]);
        float n = tanh_f(s.z + bNxv[cc] + r * (s.w + bNhv[cc]));
        hn[cc] = (1.f - zz) * n + zz * hprev[cc];
        hprev[cc] = hn[cc];
      }
      if (lane == 0) {
        u64 pk = pack4(hn[0], hn[1], hn[2], hn[3]);
        if (ringStore) {
          *(volatile u64*)(h1loc + (size_t)(t & RM) * 256 + myu) = pk;
          *(volatile u64*)(h1loc + (size_t)((t + 16) & RM) * 256 + myu) = SENT64;
        }
        astore(h1x + (size_t)(t + 1) * 256 + myu, pk);
      }
    }
  } else {
    // ---------------- layer 1 : wave owns channels ch..ch+3 ----------------
    const int ch = seat * 16 + wave * 4;
    const int myu = ch >> 2;
    // parts: 0=r_ih 1=r_hh 2=z_ih 3=z_hh 4=n_ih 5=n_hh ; 16-f16 slice each
    h2_t W[4][6][8];
    float bRv[4], bZv[4], bNxv[4], bNhv[4];
#pragma unroll
    for (int cc = 0; cc < 4; ++cc) {
      const int c = ch + cc;
#pragma unroll
      for (int g = 0; g < 3; ++g) {
        const float* pi = wih1 + (size_t)(g * HD + c) * HD + 16 * lane;
        const float* ph = whh1 + (size_t)(g * HD + c) * HD + 16 * lane;
#pragma unroll
        for (int j = 0; j < 8; ++j) {
          W[cc][2 * g][j]     = cvt2(pi[2 * j], pi[2 * j + 1]);
          W[cc][2 * g + 1][j] = cvt2(ph[2 * j], ph[2 * j + 1]);
        }
      }
      bRv[cc]  = bih1[c] + bhh1[c];
      bZv[cc]  = bih1[HD + c] + bhh1[HD + c];
      bNxv[cc] = bih1[2 * HD + c];
      bNhv[cc] = bhh1[2 * HD + c];
    }
    float hprev[4] = {0.f, 0.f, 0.f, 0.f};
    float ssum[4] = {0.f, 0.f, 0.f, 0.f};
    float ssq[4] = {0.f, 0.f, 0.f, 0.f};
    // depth-4 prefetch of the h1x agent stream: c[0]=slot t .. c[3]=slot t+3
    u64 c0[4], c1[4], c2[4], c3[4];
#pragma unroll
    for (int i = 0; i < 4; ++i) c0[i] = aload(h1x + 1 * 256 + 4 * lane + i);
#pragma unroll
    for (int i = 0; i < 4; ++i) c1[i] = aload(h1x + 2 * 256 + 4 * lane + i);
#pragma unroll
    for (int i = 0; i < 4; ++i) c2[i] = aload(h1x + 3 * 256 + 4 * lane + i);
#pragma unroll
    for (int i = 0; i < 4; ++i) c3[i] = aload(h1x + 4 * 256 + 4 * lane + i);
    for (int t = 1; t <= TT; ++t) {
      // c0 = h1x slot t = h1[t-1]; re-poll on sentinel miss
      bool bad = ((unsigned)c0[0] == SENT) | ((unsigned)c0[1] == SENT) |
                 ((unsigned)c0[2] == SENT) | ((unsigned)c0[3] == SENT);
      if (__any(bad)) {
        const u64* p = h1x + (size_t)t * 256 + 4 * lane;
        for (;;) {
          u64 a0 = aload(p), a1 = aload(p + 1), a2 = aload(p + 2), a3 = aload(p + 3);
          bool ok = ((unsigned)a0 != SENT) & ((unsigned)a1 != SENT) &
                    ((unsigned)a2 != SENT) & ((unsigned)a3 != SENT);
          if (!__any(!ok)) { c0[0] = a0; c0[1] = a1; c0[2] = a2; c0[3] = a3; break; }
        }
      }
      h2_t g1[8];
#pragma unroll
      for (int i = 0; i < 4; ++i) {
        g1[2 * i]     = __builtin_bit_cast(h2_t, (unsigned)c0[i]);
        g1[2 * i + 1] = __builtin_bit_cast(h2_t, (unsigned)(c0[i] >> 32));
      }
      float aR[4], aZ[4], aNx[4], aNh[4];
#pragma unroll
      for (int cc = 0; cc < 4; ++cc) {
        float r = 0.f, z = 0.f, n = 0.f;
#pragma unroll
        for (int j = 0; j < 8; ++j) {
          r = fdot2f(W[cc][0][j], g1[j], r);
          z = fdot2f(W[cc][2][j], g1[j], z);
          n = fdot2f(W[cc][4][j], g1[j], n);
        }
        aR[cc] = r; aZ[cc] = z; aNx[cc] = n; aNh[cc] = 0.f;
      }
      // h2[t-2]: ring slot (t-2)&31 (home L2) / shadow h2x slot t-1 (agent)
      u64 vb[4];
      pollrec(h2loc + (size_t)((t - 2) & RM) * 256 + 4 * lane,
              h2x + (size_t)(t - 1) * 256 + 4 * lane, vb, viaAgent);
      // rotate prefetch; issue slot t+4 (behind the critical poll)
#pragma unroll
      for (int i = 0; i < 4; ++i) { c0[i] = c1[i]; c1[i] = c2[i]; c2[i] = c3[i]; }
      {
        const size_t ps = (size_t)((t + 4 <= TT) ? t + 4 : TT);
        const u64* pn = h1x + ps * 256 + 4 * lane;
#pragma unroll
        for (int i = 0; i < 4; ++i) c3[i] = aload(pn + i);
      }
      h2_t g2[8];
#pragma unroll
      for (int i = 0; i < 4; ++i) {
        g2[2 * i]     = __builtin_bit_cast(h2_t, (unsigned)vb[i]);
        g2[2 * i + 1] = __builtin_bit_cast(h2_t, (unsigned)(vb[i] >> 32));
      }
#pragma unroll
      for (int cc = 0; cc < 4; ++cc) {
        float r = aR[cc], z = aZ[cc], n = aNh[cc];
#pragma unroll
        for (int j = 0; j < 8; ++j) {
          r = fdot2f(W[cc][1][j], g2[j], r);
          z = fdot2f(W[cc][3][j], g2[j], z);
          n = fdot2f(W[cc][5][j], g2[j], n);
        }
        aR[cc] = r; aZ[cc] = z; aNh[cc] = n;
      }
      float hn[4];
#pragma unroll
      for (int cc = 0; cc < 4; ++cc) {
        float4 s = reduce4(aR[cc], aZ[cc], aNx[cc], aNh[cc], lane);
        float r = sigm(s.x + bRv[cc]);
        float zz = sigm(s.y + bZv[cc]);
        float n = tanh_f(s.z + bNxv[cc] + r * (s.w + bNhv[cc]));
        hn[cc] = (1.f - zz) * n + zz * hprev[cc];
        hprev[cc] = hn[cc];
        ssum[cc] += hn[cc];
        ssq[cc] += hn[cc] * hn[cc];
      }
      if (lane == 0) {
        u64 pk = pack4(hn[0], hn[1], hn[2], hn[3]);
        if (ringStore) {
          *(volatile u64*)(h2loc + (size_t)((t - 1) & RM) * 256 + myu) = pk;
          *(volatile u64*)(h2loc + (size_t)((t + 15) & RM) * 256 + myu) = SENT64;
        }
        astore(h2x + (size_t)t * 256 + myu, pk);
      }
    }
    if (lane == 0) {
#pragma unroll
      for (int cc = 0; cc < 4; ++cc) {
        sums[ch + cc] = ssum[cc];
        sums[HD + ch + cc] = ssq[cc];
      }
    }
  }
}

// y[t] = K + sum_c h2[t,c]*A[c];  A = rsqrt(var+eps)*gamma*fc_w,
// K = fc_b + sum_c (beta*fc_w - mu*A)
__launch_bounds__(256)
__global__ void fc_bn_kernel(const unsigned* __restrict__ h2u, const float* __restrict__ sums,
                             const float* __restrict__ gamma, const float* __restrict__ beta,
                             const float* __restrict__ fcw, const float* __restrict__ fcb,
                             float* __restrict__ out)
{
  const int tid = threadIdx.x;
  const int wave = tid >> 6;
  const int lane = tid & 63;
  float A[16];
  float kp = 0.f;
#pragma unroll
  for (int j = 0; j < 16; ++j) {
    const int c = 16 * lane + j;
    float mu = sums[c] * (1.f / TT);
    float var = fmaxf(sums[HD + c] * (1.f / TT) - mu * mu, 0.f);
    float rs = rsqrtf(var + 1e-5f);
    float a = rs * gamma[c] * fcw[c];
    A[j] = a;
    kp += beta[c] * fcw[c] - mu * a;
  }
#pragma unroll
  for (int m = 32; m >= 1; m >>= 1) kp += __shfl_xor(kp, m);
  const float K = kp + fcb[0];
  const int tbase = (blockIdx.x * 4 + wave) * 16;
  for (int mm = 0; mm < 16; ++mm) {
    const int t = tbase + mm;
    const unsigned* p = h2u + (size_t)(t + 1) * 512 + 8 * lane;
    float d = 0.f;
#pragma unroll
    for (int j = 0; j < 8; ++j) {
      h2_t hp = __builtin_bit_cast(h2_t, p[j]);
      d += (float)hp.x * A[2 * j] + (float)hp.y * A[2 * j + 1];
    }
#pragma unroll
    for (int m = 32; m >= 1; m >>= 1) d += __shfl_xor(d, m);
    if (lane == 0) out[t] = K + d;
  }
}

extern "C" void kernel_launch(void* const* d_in, const int* in_sizes, int n_in,
                              void* d_out, int out_size, void* d_ws, size_t ws_size,
                              hipStream_t stream) {
  const float* x    = (const float*)d_in[0];
  const float* wih0 = (const float*)d_in[1];
  const float* whh0 = (const float*)d_in[2];
  const float* bih0 = (const float*)d_in[3];
  const float* bhh0 = (const float*)d_in[4];
  const float* wih1 = (const float*)d_in[5];
  const float* whh1 = (const float*)d_in[6];
  const float* bih1 = (const float*)d_in[7];
  const float* bhh1 = (const float*)d_in[8];
  const float* gamma = (const float*)d_in[9];
  const float* beta  = (const float*)d_in[10];
  const float* fcw   = (const float*)d_in[11];
  const float* fcb   = (const float*)d_in[12];

  const size_t SLOT = 2048;                      // 256 u64 per time slot
  const size_t RING = 32 * SLOT;                 // 64 KiB
  const size_t HIST = (size_t)(TT + 1) * SLOT;   // 33,556,480 B

  char* base = (char*)d_ws;
  unsigned* ctrl = (unsigned*)base;                          // 4 KiB
  u64* h1loc = (u64*)(base + 4096);
  u64* h2loc = (u64*)(base + 4096 + RING);
  u64* h1x   = (u64*)(base + 4096 + 2 * RING);
  u64* h2x   = (u64*)(base + 4096 + 2 * RING + HIST);
  float* sums = (float*)(base + 4096 + 2 * RING + 2 * HIST);

  hipMemsetAsync(ctrl, 0, 4096, stream);
  // rings: slot 31 = h[-1] = 0, slots 0..30 sentinel
  hipMemsetAsync(h1loc, 0x7F, RING, stream);
  hipMemsetAsync((char*)h1loc + 31 * SLOT, 0, SLOT, stream);
  hipMemsetAsync(h2loc, 0x7F, RING, stream);
  hipMemsetAsync((char*)h2loc + 31 * SLOT, 0, SLOT, stream);
  // shadow streams: slot 0 = h[-1] = 0, slots 1..TT sentinel
  hipMemsetAsync(h1x, 0, SLOT, stream);
  hipMemsetAsync((char*)h1x + SLOT, 0x7F, HIST - SLOT, stream);
  hipMemsetAsync(h2x, 0, SLOT, stream);
  hipMemsetAsync((char*)h2x + SLOT, 0x7F, HIST - SLOT, stream);

  gru_persistent<<<512, 256, 0, stream>>>(x, wih0, whh0, bih0, bhh0,
                                          wih1, whh1, bih1, bhh1,
                                          h1loc, h2loc, h1x, h2x, sums, ctrl);
  fc_bn_kernel<<<256, 256, 0, stream>>>((const unsigned*)h2x, sums, gamma, beta,
                                        fcw, fcb, (float*)d_out);
}

// Round 7
// 77988.794 us; speedup vs baseline: 2.5155x; 2.5155x over previous
//
#include <hip/hip_runtime.h>

// GRUModel: 2-layer GRU (T=16384, IN=512, H=1024) + BatchNorm(train) + FC(H->1)
//
// R7: back to the proven R2 agent-scope structure (no rings, no XCD logic).
// 128 persistent blocks (64 layer0 + 64 layer1), 4 waves/block, 4 ch/wave,
// weights in VGPRs as f16 pairs (v_dot2_f32_f16), redundant all-lane gates,
// one u64 packet store per wave per tick. Sentinel = f16 NaN 0x7F7F.
//
// New vs R2:
//  - Lane-contiguous poll layout: sample i = u64[slot*256 + 64*i + lane].
//    Each poll instruction = one clean 512B burst (4 lines) instead of a
//    2KB stride-32 scatter (16 lines x 4 sectors) => ~4x fewer TCC requests
//    on the hot slot lines (they were at per-line service saturation).
//    Weight slices are gathered to match (lane l consumes h cols 256i+4l..+3).
//  - Poll samples pre-issued at loop top, overlapped with x/g1 dot phases.
//  - Layer1: h1 via depth-4 prefetched stream + next-slot refresh (off the
//    critical h2->h2 cycle); h2 poll in flight across the g1-dot phase.

#define TT 16384
#define IND 512
#define HD 1024
#define SENT 0x7F7F7F7Fu

typedef _Float16 h2_t __attribute__((ext_vector_type(2)));
typedef unsigned long long u64;

static __device__ __forceinline__ float fdot2f(h2_t a, h2_t b, float c) {
  return __builtin_amdgcn_fdot2(a, b, c, false);
}
static __device__ __forceinline__ h2_t cvt2(float a, float b) {
  h2_t r; r.x = (_Float16)a; r.y = (_Float16)b; return r;
}
static __device__ __forceinline__ float sigm(float v) { return 1.f / (1.f + __expf(-v)); }
static __device__ __forceinline__ float tanh_f(float v) {
  v = fminf(fmaxf(v, -15.f), 15.f);
  float e = __expf(2.f * v);
  return (e - 1.f) / (e + 1.f);
}
static __device__ __forceinline__ u64 aload(const u64* p) {
  return __hip_atomic_load(p, __ATOMIC_RELAXED, __HIP_MEMORY_SCOPE_AGENT);
}
static __device__ __forceinline__ void astore(u64* p, u64 v) {
  __hip_atomic_store(p, v, __ATOMIC_RELAXED, __HIP_MEMORY_SCOPE_AGENT);
}
static __device__ __forceinline__ bool ok4(const u64 v[4]) {
  return ((unsigned)v[0] != SENT) & ((unsigned)v[1] != SENT) &
         ((unsigned)v[2] != SENT) & ((unsigned)v[3] != SENT);
}

// Reduce 4 per-lane partials across 64 lanes; all lanes get (R,Z,Nx,Nh).
static __device__ __forceinline__ float4 reduce4(float aR, float aZ, float aNx,
                                                 float aNh, int lane) {
  const bool s1 = lane & 1;
  float x1 = s1 ? aZ : aR, y1 = s1 ? aR : aZ;
  x1 += __shfl_xor(y1, 1);
  float x2 = s1 ? aNh : aNx, y2 = s1 ? aNx : aNh;
  x2 += __shfl_xor(y2, 1);
  const bool s2 = lane & 2;
  float z = s2 ? x2 : x1, w = s2 ? x1 : x2;
  z += __shfl_xor(w, 2);
  z += __shfl_xor(z, 4);
  z += __shfl_xor(z, 8);
  z += __shfl_xor(z, 16);
  z += __shfl_xor(z, 32);
  return make_float4(__shfl(z, 0), __shfl(z, 1), __shfl(z, 2), __shfl(z, 3));
}

static __device__ __forceinline__ u64 pack4(float h0, float h1, float h2, float h3) {
  unsigned lo = (unsigned)__builtin_bit_cast(unsigned short, (_Float16)h0) |
                ((unsigned)__builtin_bit_cast(unsigned short, (_Float16)h1) << 16);
  unsigned hi = (unsigned)__builtin_bit_cast(unsigned short, (_Float16)h2) |
                ((unsigned)__builtin_bit_cast(unsigned short, (_Float16)h3) << 16);
  return (u64)lo | ((u64)hi << 32);
}

__launch_bounds__(256, 1)
__global__ void gru_persistent(
    const float* __restrict__ x,
    const float* __restrict__ wih0, const float* __restrict__ whh0,
    const float* __restrict__ bih0, const float* __restrict__ bhh0,
    const float* __restrict__ wih1, const float* __restrict__ whh1,
    const float* __restrict__ bih1, const float* __restrict__ bhh1,
    u64* h1x, u64* h2x, float* sums)
{
  const int bid = blockIdx.x;
  const int tid = threadIdx.x;
  const int wave = tid >> 6;
  const int lane = tid & 63;

  if (bid < 64) {
    // ---------------- layer 0 : wave owns channels ch..ch+3 ----------------
    const int ch = bid * 16 + wave * 4;
    h2_t Wx[4][3][4];   // x-part: cols 8*lane..+7
    h2_t Wh[4][3][8];   // h-part: cols 256*i+4*lane..+3, i=0..3
    float bRv[4], bZv[4], bNxv[4], bNhv[4];
#pragma unroll
    for (int cc = 0; cc < 4; ++cc) {
      const int c = ch + cc;
#pragma unroll
      for (int g = 0; g < 3; ++g) {
        const float* pr = wih0 + (size_t)(g * HD + c) * IND + 8 * lane;
#pragma unroll
        for (int j = 0; j < 4; ++j) Wx[cc][g][j] = cvt2(pr[2 * j], pr[2 * j + 1]);
        const float* ph = whh0 + (size_t)(g * HD + c) * HD;
#pragma unroll
        for (int i = 0; i < 4; ++i)
#pragma unroll
          for (int jj = 0; jj < 2; ++jj) {
            const int col = 256 * i + 4 * lane + 2 * jj;
            Wh[cc][g][2 * i + jj] = cvt2(ph[col], ph[col + 1]);
          }
      }
      bRv[cc]  = bih0[c] + bhh0[c];
      bZv[cc]  = bih0[HD + c] + bhh0[HD + c];
      bNxv[cc] = bih0[2 * HD + c];
      bNhv[cc] = bhh0[2 * HD + c];
    }
    float hprev[4] = {0.f, 0.f, 0.f, 0.f};
    const float* px0 = x + 8 * lane;
    float4 xa = *(const float4*)px0;
    float4 xb = *(const float4*)(px0 + 4);
    u64 pa[4];
    for (int t = 0; t < TT; ++t) {
      // pre-issue poll samples for h1[t-1] (slot t; slot 0 pre-zeroed)
      const u64* pp = h1x + (size_t)t * 256 + lane;
#pragma unroll
      for (int i = 0; i < 4; ++i) pa[i] = aload(pp + 64 * i);
      h2_t xv[4];
      xv[0] = cvt2(xa.x, xa.y); xv[1] = cvt2(xa.z, xa.w);
      xv[2] = cvt2(xb.x, xb.y); xv[3] = cvt2(xb.z, xb.w);
      if (t + 1 < TT) {
        const float* pn = x + (size_t)(t + 1) * IND + 8 * lane;
        xa = *(const float4*)pn;
        xb = *(const float4*)(pn + 4);
      }
      float aR[4], aZ[4], aNx[4], aNh[4];
#pragma unroll
      for (int cc = 0; cc < 4; ++cc) {
        float r = 0.f, z = 0.f, n = 0.f;
#pragma unroll
        for (int j = 0; j < 4; ++j) {
          r = fdot2f(Wx[cc][0][j], xv[j], r);
          z = fdot2f(Wx[cc][1][j], xv[j], z);
          n = fdot2f(Wx[cc][2][j], xv[j], n);
        }
        aR[cc] = r; aZ[cc] = z; aNx[cc] = n; aNh[cc] = 0.f;
      }
      // poll (first check usually free: samples were in flight over x-dots)
      while (__any(!ok4(pa))) {
#pragma unroll
        for (int i = 0; i < 4; ++i) pa[i] = aload(pp + 64 * i);
      }
      h2_t hh[8];
#pragma unroll
      for (int i = 0; i < 4; ++i) {
        hh[2 * i]     = __builtin_bit_cast(h2_t, (unsigned)pa[i]);
        hh[2 * i + 1] = __builtin_bit_cast(h2_t, (unsigned)(pa[i] >> 32));
      }
#pragma unroll
      for (int cc = 0; cc < 4; ++cc) {
        float r = aR[cc], z = aZ[cc], n = aNh[cc];
#pragma unroll
        for (int j = 0; j < 8; ++j) {
          r = fdot2f(Wh[cc][0][j], hh[j], r);
          z = fdot2f(Wh[cc][1][j], hh[j], z);
          n = fdot2f(Wh[cc][2][j], hh[j], n);
        }
        aR[cc] = r; aZ[cc] = z; aNh[cc] = n;
      }
      float hn[4];
#pragma unroll
      for (int cc = 0; cc < 4; ++cc) {
        float4 s = reduce4(aR[cc], aZ[cc], aNx[cc], aNh[cc], lane);
        float r = sigm(s.x + bRv[cc]);
        float zz = sigm(s.y + bZv[cc]);
        float n = tanh_f(s.z + bNxv[cc] + r * (s.w + bNhv[cc]));
        hn[cc] = (1.f - zz) * n + zz * hprev[cc];
        hprev[cc] = hn[cc];
      }
      if (lane == 0)
        astore(h1x + (size_t)(t + 1) * 256 + (ch >> 2), pack4(hn[0], hn[1], hn[2], hn[3]));
    }
  } else {
    // ---------------- layer 1 : wave owns channels ch..ch+3 ----------------
    const int ch = (bid - 64) * 16 + wave * 4;
    // parts: 0=r_ih 1=r_hh 2=z_ih 3=z_hh 4=n_ih 5=n_hh ;
    // slice cols 256*i+4*lane..+3, i=0..3 (matches packet layout)
    h2_t W[4][6][8];
    float bRv[4], bZv[4], bNxv[4], bNhv[4];
#pragma unroll
    for (int cc = 0; cc < 4; ++cc) {
      const int c = ch + cc;
#pragma unroll
      for (int g = 0; g < 3; ++g) {
        const float* pi = wih1 + (size_t)(g * HD + c) * HD;
        const float* ph = whh1 + (size_t)(g * HD + c) * HD;
#pragma unroll
        for (int i = 0; i < 4; ++i)
#pragma unroll
          for (int jj = 0; jj < 2; ++jj) {
            const int col = 256 * i + 4 * lane + 2 * jj;
            W[cc][2 * g][2 * i + jj]     = cvt2(pi[col], pi[col + 1]);
            W[cc][2 * g + 1][2 * i + jj] = cvt2(ph[col], ph[col + 1]);
          }
      }
      bRv[cc]  = bih1[c] + bhh1[c];
      bZv[cc]  = bih1[HD + c] + bhh1[HD + c];
      bNxv[cc] = bih1[2 * HD + c];
      bNhv[cc] = bhh1[2 * HD + c];
    }
    float hprev[4] = {0.f, 0.f, 0.f, 0.f};
    float ssum[4] = {0.f, 0.f, 0.f, 0.f};
    float ssq[4] = {0.f, 0.f, 0.f, 0.f};
    // depth-4 prefetch of the h1x stream: c0=slot t, c1=t+1, c2=t+2, c3=t+3
    u64 c0[4], c1[4], c2[4], c3[4];
#pragma unroll
    for (int i = 0; i < 4; ++i) c0[i] = aload(h1x + 1 * 256 + 64 * i + lane);
#pragma unroll
    for (int i = 0; i < 4; ++i) c1[i] = aload(h1x + 2 * 256 + 64 * i + lane);
#pragma unroll
    for (int i = 0; i < 4; ++i) c2[i] = aload(h1x + 3 * 256 + 64 * i + lane);
#pragma unroll
    for (int i = 0; i < 4; ++i) c3[i] = aload(h1x + 4 * 256 + 64 * i + lane);
    u64 pa[4];
    for (int t = 1; t <= TT; ++t) {
      // pre-issue poll samples for h2[t-2] (h2x slot t-1; slot 0 pre-zeroed)
      const u64* pp = h2x + (size_t)(t - 1) * 256 + lane;
#pragma unroll
      for (int i = 0; i < 4; ++i) pa[i] = aload(pp + 64 * i);
      // c0 = h1x slot t = h1[t-1]; re-poll on sentinel miss (layer0 leads)
      if (__any(!ok4(c0))) {
        const u64* p = h1x + (size_t)t * 256 + lane;
        do {
#pragma unroll
          for (int i = 0; i < 4; ++i) c0[i] = aload(p + 64 * i);
        } while (__any(!ok4(c0)));
      }
      h2_t g1[8];
#pragma unroll
      for (int i = 0; i < 4; ++i) {
        g1[2 * i]     = __builtin_bit_cast(h2_t, (unsigned)c0[i]);
        g1[2 * i + 1] = __builtin_bit_cast(h2_t, (unsigned)(c0[i] >> 32));
      }
      float aR[4], aZ[4], aNx[4], aNh[4];
#pragma unroll
      for (int cc = 0; cc < 4; ++cc) {
        float r = 0.f, z = 0.f, n = 0.f;
#pragma unroll
        for (int j = 0; j < 8; ++j) {
          r = fdot2f(W[cc][0][j], g1[j], r);
          z = fdot2f(W[cc][2][j], g1[j], z);
          n = fdot2f(W[cc][4][j], g1[j], n);
        }
        aR[cc] = r; aZ[cc] = z; aNx[cc] = n; aNh[cc] = 0.f;
      }
      // h2[t-2] poll (samples were in flight across the g1 phase)
      while (__any(!ok4(pa))) {
#pragma unroll
        for (int i = 0; i < 4; ++i) pa[i] = aload(pp + 64 * i);
      }
      // rotate h1 prefetch; issue slot t+4; refresh next tick's slot if stale
#pragma unroll
      for (int i = 0; i < 4; ++i) { c0[i] = c1[i]; c1[i] = c2[i]; c2[i] = c3[i]; }
      {
        const size_t ps = (size_t)((t + 4 <= TT) ? t + 4 : TT);
        const u64* pn = h1x + ps * 256 + lane;
#pragma unroll
        for (int i = 0; i < 4; ++i) c3[i] = aload(pn + i * 64);
        if (__any(!ok4(c0))) {
          const u64* pr = h1x + (size_t)(t + 1 <= TT ? t + 1 : TT) * 256 + lane;
#pragma unroll
          for (int i = 0; i < 4; ++i) c0[i] = aload(pr + i * 64);
        }
      }
      h2_t g2[8];
#pragma unroll
      for (int i = 0; i < 4; ++i) {
        g2[2 * i]     = __builtin_bit_cast(h2_t, (unsigned)pa[i]);
        g2[2 * i + 1] = __builtin_bit_cast(h2_t, (unsigned)(pa[i] >> 32));
      }
#pragma unroll
      for (int cc = 0; cc < 4; ++cc) {
        float r = aR[cc], z = aZ[cc], n = aNh[cc];
#pragma unroll
        for (int j = 0; j < 8; ++j) {
          r = fdot2f(W[cc][1][j], g2[j], r);
          z = fdot2f(W[cc][3][j], g2[j], z);
          n = fdot2f(W[cc][5][j], g2[j], n);
        }
        aR[cc] = r; aZ[cc] = z; aNh[cc] = n;
      }
      float hn[4];
#pragma unroll
      for (int cc = 0; cc < 4; ++cc) {
        float4 s = reduce4(aR[cc], aZ[cc], aNx[cc], aNh[cc], lane);
        float r = sigm(s.x + bRv[cc]);
        float zz = sigm(s.y + bZv[cc]);
        float n = tanh_f(s.z + bNxv[cc] + r * (s.w + bNhv[cc]));
        hn[cc] = (1.f - zz) * n + zz * hprev[cc];
        hprev[cc] = hn[cc];
        ssum[cc] += hn[cc];
        ssq[cc] += hn[cc] * hn[cc];
      }
      if (lane == 0)
        astore(h2x + (size_t)t * 256 + (ch >> 2), pack4(hn[0], hn[1], hn[2], hn[3]));
    }
    if (lane == 0) {
#pragma unroll
      for (int cc = 0; cc < 4; ++cc) {
        sums[ch + cc] = ssum[cc];
        sums[HD + ch + cc] = ssq[cc];
      }
    }
  }
}

// y[t] = K + sum_c h2[t,c]*A[c];  A = rsqrt(var+eps)*gamma*fc_w,
// K = fc_b + sum_c (beta*fc_w - mu*A)
__launch_bounds__(256)
__global__ void fc_bn_kernel(const unsigned* __restrict__ h2u, const float* __restrict__ sums,
                             const float* __restrict__ gamma, const float* __restrict__ beta,
                             const float* __restrict__ fcw, const float* __restrict__ fcb,
                             float* __restrict__ out)
{
  const int tid = threadIdx.x;
  const int wave = tid >> 6;
  const int lane = tid & 63;
  float A[16];
  float kp = 0.f;
#pragma unroll
  for (int j = 0; j < 16; ++j) {
    const int c = 16 * lane + j;
    float mu = sums[c] * (1.f / TT);
    float var = fmaxf(sums[HD + c] * (1.f / TT) - mu * mu, 0.f);
    float rs = rsqrtf(var + 1e-5f);
    float a = rs * gamma[c] * fcw[c];
    A[j] = a;
    kp += beta[c] * fcw[c] - mu * a;
  }
#pragma unroll
  for (int m = 32; m >= 1; m >>= 1) kp += __shfl_xor(kp, m);
  const float K = kp + fcb[0];
  const int tbase = (blockIdx.x * 4 + wave) * 16;
  for (int mm = 0; mm < 16; ++mm) {
    const int t = tbase + mm;
    const unsigned* p = h2u + (size_t)(t + 1) * 512 + 8 * lane;
    float d = 0.f;
#pragma unroll
    for (int j = 0; j < 8; ++j) {
      h2_t hp = __builtin_bit_cast(h2_t, p[j]);
      d += (float)hp.x * A[2 * j] + (float)hp.y * A[2 * j + 1];
    }
#pragma unroll
    for (int m = 32; m >= 1; m >>= 1) d += __shfl_xor(d, m);
    if (lane == 0) out[t] = K + d;
  }
}

extern "C" void kernel_launch(void* const* d_in, const int* in_sizes, int n_in,
                              void* d_out, int out_size, void* d_ws, size_t ws_size,
                              hipStream_t stream) {
  const float* x    = (const float*)d_in[0];
  const float* wih0 = (const float*)d_in[1];
  const float* whh0 = (const float*)d_in[2];
  const float* bih0 = (const float*)d_in[3];
  const float* bhh0 = (const float*)d_in[4];
  const float* wih1 = (const float*)d_in[5];
  const float* whh1 = (const float*)d_in[6];
  const float* bih1 = (const float*)d_in[7];
  const float* bhh1 = (const float*)d_in[8];
  const float* gamma = (const float*)d_in[9];
  const float* beta  = (const float*)d_in[10];
  const float* fcw   = (const float*)d_in[11];
  const float* fcb   = (const float*)d_in[12];

  const size_t SLOT = 2048;                      // 256 u64 per time slot
  const size_t HIST = (size_t)(TT + 1) * SLOT;   // 33,556,480 B per stream

  u64* h1x = (u64*)d_ws;
  u64* h2x = (u64*)((char*)d_ws + HIST);
  float* sums = (float*)((char*)d_ws + 2 * HIST);

  // slot 0 = h[-1] = 0 ; slots 1..TT = f16 NaN sentinel (0x7F7F)
  hipMemsetAsync(h1x, 0, SLOT, stream);
  hipMemsetAsync((char*)h1x + SLOT, 0x7F, HIST - SLOT, stream);
  hipMemsetAsync(h2x, 0, SLOT, stream);
  hipMemsetAsync((char*)h2x + SLOT, 0x7F, HIST - SLOT, stream);

  gru_persistent<<<128, 256, 0, stream>>>(x, wih0, whh0, bih0, bhh0,
                                          wih1, whh1, bih1, bhh1,
                                          h1x, h2x, sums);
  fc_bn_kernel<<<256, 256, 0, stream>>>((const unsigned*)h2x, sums, gamma, beta,
                                        fcw, fcb, (float*)d_out);
}